// Round 11
// baseline (742.880 us; speedup 1.0000x reference)
//
#include <hip/hip_runtime.h>
#include <math.h>

typedef _Float16 f16;
typedef __attribute__((ext_vector_type(8))) _Float16 f16x8;
typedef __attribute__((ext_vector_type(16))) float f32x16;

union U64x2 { unsigned long long u[2]; f16x8 v; };
union Q16   { uint4 q; unsigned long long u[2]; };

constexpr int ilog2c(int x) { return x <= 1 ? 0 : 1 + ilog2c(x >> 1); }

__device__ __forceinline__ float fast_tanh(float x) {
    float e = __expf(2.f * x);
    return (e - 1.f) / (e + 1.f);
}

// ===========================================================================
// fp16 MFMA implicit-GEMM conv/deconv (k4 s2 p1), NHWC activations.
// A-operand = X (sp rows), B-operand = W (co cols) => D: row=sp, col=co.
// SPT generic (128/256): TPRX=256/SPT threads co-stage each 64-f16 X row.
// KS==1 everywhere now; fused BN sum/sumsq via shfl pair-reduce + atomicAdd.
// __launch_bounds__(256,3): LDS 26KB @SPT=128 -> 3 blocks/CU for barrier
// overlap (round-10 showed 1 block/CU grids stall on the barrier drain).
// ===========================================================================
template<int CIN,int IH,int IW,int OH,int OW,int COUT,int COB,int SPT,int KS,
         int CO_FR,bool DEC>
__global__ __launch_bounds__(256,3) void mfma_conv(
    const f16* __restrict__ xin, const f16* __restrict__ wp,
    f16* __restrict__ out16, float* __restrict__ out32, size_t ps,
    float* __restrict__ psumF, float* __restrict__ psqF)
{
    constexpr int OHo  = DEC ? OH/2 : OH;
    constexpr int OWo  = DEC ? OW/2 : OW;
    constexpr int KTOT = CIN * (DEC ? 4 : 16);
    constexpr int CH   = (KTOT/64) / KS;
    constexpr int RPT  = CIN / 64;
    constexpr int RSH  = (RPT==1?0:RPT==2?1:RPT==4?2:3);
    constexpr int WSTR = CIN * 16;
    constexpr int TPR  = 256 / COB;
    constexpr int NU4  = 8 / TPR;
    constexpr int SPB  = OHo * OWo;
    constexpr int LSPB = ilog2c(SPB);
    constexpr int LOWo = ilog2c(OWo);
    constexpr int B    = SPT / 64;        // sp fragments per wave
    constexpr int TPRX = 256 / SPT;       // threads per X LDS row
    constexpr int XU   = 16 / TPRX;       // u64 staged per thread

    __shared__ unsigned long long Xs[SPT*17];
    __shared__ unsigned long long Wls[COB*17];

    const int t   = threadIdx.x;
    const int bx  = blockIdx.x;
    const int cob = blockIdx.y;
    const int bz  = blockIdx.z;
    const int par = DEC ? (bz & 3) : 0;
    const int ks  = DEC ? (bz >> 2) : bz;
    const int poh = par >> 1, pw = par & 1;

    const int xrow  = t / TPRX;
    const int xpart = t % TPRX;
    const int gsp_s = bx*SPT + xrow;
    const int img_s = gsp_s >> LSPB;
    const int r_s   = gsp_s & (SPB-1);
    const int oy_s  = r_s >> LOWo;
    const int ox_s  = r_s & (OWo-1);

    const int wco   = t / TPR;
    const int wpart = t % TPR;
    const f16* wbase = wp + (size_t)(cob*COB + wco)*WSTR + wpart*(64/TPR);

    const int wave = t >> 6, lane = t & 63, half = lane >> 5, l31 = lane & 31;
    const int co_w = (wave >> 1) * (CO_FR*32);
    const int sp_w = (wave & 1) * (SPT/2);

    f32x16 acc[CO_FR][B];
    #pragma unroll
    for (int i = 0; i < CO_FR; ++i)
        #pragma unroll
        for (int b = 0; b < B; ++b)
            #pragma unroll
            for (int r = 0; r < 16; ++r) acc[i][b][r] = 0.f;

    for (int cc = 0; cc < CH; ++cc) {
        const int gc  = ks*CH + cc;
        const int tap = gc >> RSH;
        const int ci0 = (gc & (RPT-1)) << 6;
        int kh, kw, ih, iw;
        if (DEC) {
            const int t2h = tap >> 1, t2w = tap & 1;
            kh = (1-poh) + 2*t2h; kw = (1-pw) + 2*t2w;
            ih = oy_s + poh - t2h; iw = ox_s + pw - t2w;
        } else {
            kh = tap >> 2; kw = tap & 3;
            ih = 2*oy_s - 1 + kh; iw = 2*ox_s - 1 + kw;
        }
        const int woff = (kh*4 + kw)*CIN + ci0;

        if (cc) __syncthreads();
        {
            const uint4* src = (const uint4*)(wbase + woff);
            #pragma unroll
            for (int j = 0; j < NU4; ++j) {
                Q16 v; v.q = src[j];
                const int u0 = wco*17 + wpart*(NU4*2) + j*2;
                Wls[u0]   = v.u[0];
                Wls[u0+1] = v.u[1];
            }
        }
        {
            const bool ok = (unsigned)ih < (unsigned)IH && (unsigned)iw < (unsigned)IW;
            const int u0 = xrow*17 + xpart*XU;
            if (ok) {
                const uint4* src = (const uint4*)
                    (xin + ((size_t)(img_s*IH + ih)*IW + iw)*CIN + ci0 + xpart*(XU*4));
                #pragma unroll
                for (int j = 0; j < XU/2; ++j) {
                    Q16 v; v.q = src[j];
                    Xs[u0 + j*2]   = v.u[0];
                    Xs[u0 + j*2+1] = v.u[1];
                }
            } else {
                #pragma unroll
                for (int j = 0; j < XU; ++j) Xs[u0 + j] = 0ull;
            }
        }
        __syncthreads();

        #pragma unroll
        for (int kk = 0; kk < 4; ++kk) {
            const int uo = kk*4 + 2*half;
            f16x8 wf[CO_FR], xf[B];
            #pragma unroll
            for (int i = 0; i < CO_FR; ++i) {
                U64x2 u; const int rw = (co_w + i*32 + l31)*17 + uo;
                u.u[0] = Wls[rw]; u.u[1] = Wls[rw+1]; wf[i] = u.v;
            }
            #pragma unroll
            for (int b = 0; b < B; ++b) {
                U64x2 u; const int rx = (sp_w + b*32 + l31)*17 + uo;
                u.u[0] = Xs[rx]; u.u[1] = Xs[rx+1]; xf[b] = u.v;
            }
            #pragma unroll
            for (int i = 0; i < CO_FR; ++i)
                #pragma unroll
                for (int b = 0; b < B; ++b)
                    acc[i][b] = __builtin_amdgcn_mfma_f32_32x32x16_f16(
                        xf[b], wf[i], acc[i][b], 0, 0, 0);
        }
    }

    #pragma unroll
    for (int b = 0; b < B; ++b) {
        #pragma unroll
        for (int q = 0; q < 4; ++q) {
            #pragma unroll
            for (int r2 = 0; r2 < 4; ++r2) {
                const int sp_loc = sp_w + b*32 + q*8 + 4*half + r2;
                const int gsp    = bx*SPT + sp_loc;
                size_t base;
                if (DEC) {
                    const int img = gsp >> LSPB;
                    const int r   = gsp & (SPB-1);
                    const int oh  = 2*(r >> LOWo) + poh;
                    const int ow  = 2*(r & (OWo-1)) + pw;
                    base = ((size_t)(img*OH + oh)*OW + ow)*COUT + cob*COB;
                } else {
                    base = (size_t)gsp*COUT + cob*COB;
                }
                #pragma unroll
                for (int i = 0; i < CO_FR; ++i) {
                    const int co_l = co_w + i*32 + l31;
                    const float v  = acc[i][b][q*4 + r2];
                    if (KS == 1) out16[base + co_l] = (_Float16)v;
                    else         out32[(size_t)ks*ps + base + co_l] = v;
                }
            }
        }
    }

    if (KS == 1 && psumF != nullptr) {
        #pragma unroll
        for (int i = 0; i < CO_FR; ++i) {
            float s = 0.f, q = 0.f;
            #pragma unroll
            for (int b = 0; b < B; ++b)
                #pragma unroll
                for (int r = 0; r < 16; ++r) {
                    const float v = acc[i][b][r];
                    s += v; q += v * v;
                }
            s += __shfl_down(s, 32);
            q += __shfl_down(q, 32);
            if (half == 0) {
                const int co = cob*COB + co_w + i*32 + l31;
                atomicAdd(psumF + co, s);
                atomicAdd(psqF + co, q);
            }
        }
    }
}

// ---------------------------------------------------------------------------
// conv1 via MFMA + fused BN stats (verified rounds 8-10)
// ---------------------------------------------------------------------------
__global__ __launch_bounds__(256,2) void conv1_mfma(
    const f16* __restrict__ xp, const f16* __restrict__ wp,
    f16* __restrict__ out, float* __restrict__ psumF, float* __restrict__ psqF)
{
    __shared__ unsigned long long Xs[256*17];
    __shared__ unsigned long long Wls[64*17];
    const int t = threadIdx.x, bx = blockIdx.x;

    {
        const int r = t >> 2, part = t & 3;
        const uint4* src = (const uint4*)(wp + r*64 + part*16);
        Q16 v0; v0.q = src[0];
        Q16 v1; v1.q = src[1];
        const int u0 = r*17 + part*4;
        Wls[u0]   = v0.u[0]; Wls[u0+1] = v0.u[1];
        Wls[u0+2] = v1.u[0]; Wls[u0+3] = v1.u[1];
    }
    {
        const int gsp = bx*256 + t;
        const int n = gsp >> 10, r = gsp & 1023;
        const int oy = r >> 5, ox = r & 31;
        const int ih0 = 2*oy - 1, iw0 = 2*ox - 1;
        const int u0 = t*17;
        #pragma unroll
        for (int tap = 0; tap < 16; ++tap) {
            const int ih = ih0 + (tap >> 2), iw = iw0 + (tap & 3);
            unsigned long long v = 0ull;
            if ((unsigned)ih < 64u && (unsigned)iw < 64u)
                v = *(const unsigned long long*)(xp + (((size_t)n*64 + ih)*64 + iw)*4);
            Xs[u0 + tap] = v;
        }
    }
    __syncthreads();

    const int wave = t >> 6, lane = t & 63, half = lane >> 5, l31 = lane & 31;
    const int co_w = (wave >> 1) * 32;
    const int sp_w = (wave & 1) * 128;

    f32x16 acc[4];
    #pragma unroll
    for (int b = 0; b < 4; ++b)
        #pragma unroll
        for (int r = 0; r < 16; ++r) acc[b][r] = 0.f;

    #pragma unroll
    for (int kk = 0; kk < 4; ++kk) {
        const int uo = kk*4 + 2*half;
        U64x2 uw; const int rw = (co_w + l31)*17 + uo;
        uw.u[0] = Wls[rw]; uw.u[1] = Wls[rw+1];
        #pragma unroll
        for (int b = 0; b < 4; ++b) {
            U64x2 ux; const int rx = (sp_w + b*32 + l31)*17 + uo;
            ux.u[0] = Xs[rx]; ux.u[1] = Xs[rx+1];
            acc[b] = __builtin_amdgcn_mfma_f32_32x32x16_f16(
                ux.v, uw.v, acc[b], 0, 0, 0);
        }
    }
    #pragma unroll
    for (int b = 0; b < 4; ++b)
        #pragma unroll
        for (int q = 0; q < 4; ++q)
            #pragma unroll
            for (int r2 = 0; r2 < 4; ++r2) {
                const int sp_loc = sp_w + b*32 + q*8 + 4*half + r2;
                out[(size_t)(bx*256 + sp_loc)*64 + co_w + l31] =
                    (_Float16)acc[b][q*4 + r2];
            }

    float s = 0.f, q = 0.f;
    #pragma unroll
    for (int b = 0; b < 4; ++b)
        #pragma unroll
        for (int r = 0; r < 16; ++r) {
            const float v = acc[b][r];
            s += v; q += v * v;
        }
    s += __shfl_down(s, 32);
    q += __shfl_down(q, 32);
    if (half == 0) {
        const int co = co_w + l31;
        atomicAdd(psumF + co, s);
        atomicAdd(psqF + co, q);
    }
}

// ---------------------------------------------------------------------------
// deconv4 (64->3) via MFMA, COUT padded to 32 (verified round 9)
// ---------------------------------------------------------------------------
__global__ __launch_bounds__(256,2) void deconv4_mfma(
    const f16* __restrict__ xin, const f16* __restrict__ wp,
    float* __restrict__ out)
{
    __shared__ unsigned long long Xs[256*17];
    __shared__ unsigned long long Wls[32*17];

    const int t   = threadIdx.x;
    const int bx  = blockIdx.x;
    const int par = blockIdx.y;
    const int poh = par >> 1, pw = par & 1;

    const int gsp_s = bx*256 + t;
    const int img_s = gsp_s >> 10;
    const int r_s   = gsp_s & 1023;
    const int oy_s  = r_s >> 5;
    const int ox_s  = r_s & 31;

    const int wco   = t >> 3;
    const int wpart = t & 7;

    const int wave = t >> 6, lane = t & 63, half = lane >> 5, l31 = lane & 31;
    const int sp_w = wave * 64;

    f32x16 acc[2];
    #pragma unroll
    for (int b = 0; b < 2; ++b)
        #pragma unroll
        for (int r = 0; r < 16; ++r) acc[b][r] = 0.f;

    for (int cc = 0; cc < 4; ++cc) {
        const int t2h = cc >> 1, t2w = cc & 1;
        const int kh = (1-poh) + 2*t2h, kw = (1-pw) + 2*t2w;
        const int ih = oy_s + poh - t2h, iw = ox_s + pw - t2w;

        if (cc) __syncthreads();
        {
            Q16 v; v.q = *(const uint4*)(wp + wco*1024 + (kh*4 + kw)*64 + wpart*8);
            const int u0 = wco*17 + wpart*2;
            Wls[u0] = v.u[0]; Wls[u0+1] = v.u[1];
        }
        {
            const bool ok = (unsigned)ih < 32u && (unsigned)iw < 32u;
            const int u0 = t*17;
            if (ok) {
                const uint4* src = (const uint4*)
                    (xin + ((size_t)(img_s*32 + ih)*32 + iw)*64);
                #pragma unroll
                for (int j = 0; j < 8; ++j) {
                    Q16 v; v.q = src[j];
                    Xs[u0 + j*2]   = v.u[0];
                    Xs[u0 + j*2+1] = v.u[1];
                }
            } else {
                #pragma unroll
                for (int j = 0; j < 16; ++j) Xs[u0 + j] = 0ull;
            }
        }
        __syncthreads();

        #pragma unroll
        for (int kk = 0; kk < 4; ++kk) {
            const int uo = kk*4 + 2*half;
            U64x2 uw; const int rw = l31*17 + uo;
            uw.u[0] = Wls[rw]; uw.u[1] = Wls[rw+1];
            #pragma unroll
            for (int b = 0; b < 2; ++b) {
                U64x2 ux; const int rx = (sp_w + b*32 + l31)*17 + uo;
                ux.u[0] = Xs[rx]; ux.u[1] = Xs[rx+1];
                acc[b] = __builtin_amdgcn_mfma_f32_32x32x16_f16(
                    uw.v, ux.v, acc[b], 0, 0, 0);
            }
        }
    }

    if (half == 0) {
        #pragma unroll
        for (int b = 0; b < 2; ++b) {
            const int gsp = bx*256 + sp_w + b*32 + l31;
            const int img = gsp >> 10;
            const int r   = gsp & 1023;
            const int oh  = 2*(r >> 5) + poh;
            const int ow  = 2*(r & 31) + pw;
            #pragma unroll
            for (int co = 0; co < 3; ++co)
                out[(((size_t)img*3 + co)*64 + oh)*64 + ow] =
                    fast_tanh(acc[b][co]);
        }
    }
}

// ---------------------------------------------------------------------------
// prep kernels (verified)
// ---------------------------------------------------------------------------
__global__ __launch_bounds__(256) void prep_x(
    const float* __restrict__ x, f16* __restrict__ xp)
{
    const int i = blockIdx.x*256 + threadIdx.x;
    const int n = i >> 12, p = i & 4095;
    const float* b = x + (size_t)n*12288 + p;
    union { _Float16 h[4]; unsigned long long u; } o;
    o.h[0] = (_Float16)b[0];
    o.h[1] = (_Float16)b[4096];
    o.h[2] = (_Float16)b[8192];
    o.h[3] = (_Float16)0.f;
    *(unsigned long long*)(xp + (size_t)i*4) = o.u;
}

__global__ __launch_bounds__(256) void prep_w1(
    const float* __restrict__ w1, f16* __restrict__ wp)
{
    const int e = blockIdx.x*256 + threadIdx.x;
    const int co = e >> 6, k = e & 63, tap = k >> 2, ci = k & 3;
    const float v = (ci < 3) ? w1[(co*3 + ci)*16 + tap] : 0.f;
    wp[e] = (_Float16)v;
}

__global__ __launch_bounds__(256) void prep_w4(
    const float* __restrict__ dw4, f16* __restrict__ wp)
{
    const int e = blockIdx.x*256 + threadIdx.x;
    const int co = e >> 10, r = e & 1023, khw = r >> 6, ci = r & 63;
    const float v = (co < 3) ? dw4[(ci*3 + co)*16 + khw] : 0.f;
    wp[e] = (_Float16)v;
}

__global__ __launch_bounds__(256) void prep_w(
    const float* __restrict__ w2, const float* __restrict__ w3,
    const float* __restrict__ w4, const float* __restrict__ dw1,
    const float* __restrict__ dw2, const float* __restrict__ dw3,
    f16* __restrict__ dst)
{
    const int e = blockIdx.x*256 + threadIdx.x;
    float v;
    if (e < 131072) {
        int co = e >> 10, r = e & 1023, khw = r >> 6, ci = r & 63;
        v = w2[(co*64 + ci)*16 + khw];
    } else if (e < 655360) {
        int l = e - 131072;
        int co = l >> 11, r = l & 2047, khw = r >> 7, ci = r & 127;
        v = w3[(co*128 + ci)*16 + khw];
    } else if (e < 2752512) {
        int l = e - 655360;
        int co = l >> 12, r = l & 4095, khw = r >> 8, ci = r & 255;
        v = w4[(co*256 + ci)*16 + khw];
    } else if (e < 4849664) {
        int l = e - 2752512;
        int co = l >> 13, r = l & 8191, khw = r >> 9, ci = r & 511;
        v = dw1[(ci*256 + co)*16 + khw];
    } else if (e < 5373952) {
        int l = e - 4849664;
        int co = l >> 12, r = l & 4095, khw = r >> 8, ci = r & 255;
        v = dw2[(ci*128 + co)*16 + khw];
    } else {
        int l = e - 5373952;
        int co = l >> 11, r = l & 2047, khw = r >> 7, ci = r & 127;
        v = dw3[(ci*64 + co)*16 + khw];
    }
    dst[e] = (_Float16)v;
}

// ---------------------------------------------------------------------------
// BN finalize + fused affine/activation
// ---------------------------------------------------------------------------
__global__ __launch_bounds__(256) void bn_finalize(
    const float* __restrict__ psum, const float* __restrict__ psq,
    const float* __restrict__ gamma, const float* __restrict__ beta,
    float* __restrict__ scale, float* __restrict__ shift,
    int C, int S, float inv_count)
{
    int c = blockIdx.x * 256 + threadIdx.x;
    if (c >= C) return;
    float s = 0.f, q = 0.f;
    for (int i = 0; i < S; ++i) { s += psum[c*S + i]; q += psq[c*S + i]; }
    float m   = s * inv_count;
    float var = q * inv_count - m * m;
    var = var < 0.f ? 0.f : var;
    float sc = gamma[c] * rsqrtf(var + 1e-5f);
    scale[c] = sc;
    shift[c] = beta[c] - m * sc;
}

__global__ __launch_bounds__(256) void bn_act16(
    f16* __restrict__ x, const float* __restrict__ sc, const float* __restrict__ sh,
    int Cmask, float slope)
{
    const size_t i8 = ((size_t)blockIdx.x*256 + threadIdx.x) * 8;
    union { uint4 u; _Float16 h[8]; } a;
    a.u = *(const uint4*)(x + i8);
    const int c0 = (int)(i8 & (size_t)Cmask);
    #pragma unroll
    for (int j = 0; j < 8; ++j) {
        float v = (float)a.h[j] * sc[c0+j] + sh[c0+j];
        a.h[j] = (_Float16)(v >= 0.f ? v : slope * v);
    }
    *(uint4*)(x + i8) = a.u;
}

__global__ __launch_bounds__(256) void chanlin16(
    const f16* __restrict__ in, const float* __restrict__ w,
    const float* __restrict__ bias, f16* __restrict__ out)
{
    const int i = blockIdx.x*256 + threadIdx.x;
    const int c  = i & 511;
    const int bt = i >> 9;
    const int b  = bt >> 4, tt = bt & 15;
    const f16* src = in + ((size_t)b*16)*512 + c;
    const float* wr = w + ((size_t)c*16 + tt)*16;
    float acc = bias[c*16 + tt];
    #pragma unroll
    for (int s = 0; s < 16; ++s)
        acc = fmaf((float)src[s*512], wr[s], acc);
    out[i] = (_Float16)acc;
}

extern "C" void kernel_launch(void* const* d_in, const int* in_sizes, int n_in,
                              void* d_out, int out_size, void* d_ws, size_t ws_size,
                              hipStream_t stream)
{
    const float* x   = (const float*)d_in[0];
    const float* w1  = (const float*)d_in[1];
    const float* w2  = (const float*)d_in[2];
    const float* w3  = (const float*)d_in[3];
    const float* w4  = (const float*)d_in[4];
    const float* g1  = (const float*)d_in[5];
    const float* b1  = (const float*)d_in[6];
    const float* g2  = (const float*)d_in[7];
    const float* b2  = (const float*)d_in[8];
    const float* g3  = (const float*)d_in[9];
    const float* b3  = (const float*)d_in[10];
    const float* g4  = (const float*)d_in[11];
    const float* b4  = (const float*)d_in[12];
    const float* cww = (const float*)d_in[13];
    const float* cwb = (const float*)d_in[14];
    const float* dw1 = (const float*)d_in[15];
    const float* dw2 = (const float*)d_in[16];
    const float* dw3 = (const float*)d_in[17];
    const float* dw4 = (const float*)d_in[18];
    const float* dg1 = (const float*)d_in[19];
    const float* db1 = (const float*)d_in[20];
    const float* dg2 = (const float*)d_in[21];
    const float* db2 = (const float*)d_in[22];
    const float* dg3 = (const float*)d_in[23];
    const float* db3 = (const float*)d_in[24];

    char* WS = (char*)d_ws;
    float* scale = (float*)(WS + 131072);
    float* shift = (float*)(WS + 133120);
    float* fst   = (float*)(WS + 196608);
    f16* slotA   = (f16*)(WS + 262144);
    f16* slotB   = (f16*)(WS + 262144 + 33554432);
    f16* wprep   = (f16*)(WS + 84148224);
    f16* wprep1  = wprep + 5505024;
    f16* wprep4  = wprep1 + 4096;

    f16*   A_hi  = slotA + 8388608;          // +16.78 MB inside slotA
    f16*   xpack = slotA;

    // per-layer fused stat slots: psum = fst + L*1024, psq = +512
    float* fs0 = fst;          float* fs1 = fst + 1024;
    float* fs2 = fst + 2048;   float* fs3 = fst + 3072;
    float* fs4 = fst + 4096;   float* fs5 = fst + 5120;
    float* fs6 = fst + 6144;

    hipMemsetAsync(fst, 0, 28672, stream);
    prep_w<<<21504, 256, 0, stream>>>(w2, w3, w4, dw1, dw2, dw3, wprep);
    prep_w1<<<16, 256, 0, stream>>>(w1, wprep1);
    prep_w4<<<128, 256, 0, stream>>>(dw4, wprep4);
    prep_x<<<4096, 256, 0, stream>>>(x, xpack);

    // ---- conv1 (MFMA + fused stats): xpack(slotA) -> slotB ----
    conv1_mfma<<<1024, 256, 0, stream>>>(xpack, wprep1, slotB, fs0, fs0 + 512);
    bn_finalize<<<1, 256, 0, stream>>>(fs0, fs0 + 512, g1, b1, scale, shift, 64, 1, 1.f/262144.f);
    bn_act16<<<8192, 256, 0, stream>>>(slotB, scale, shift, 63, 0.2f);

    // ---- conv2 (SPT=128, COB=64): slotB -> slotA(lo), 1024 blocks ----
    mfma_conv<64,32,32,16,16,128, 64,128,1,1,false><<<dim3(512,2,1), 256, 0, stream>>>(
        slotB, wprep, slotA, nullptr, 0, fs1, fs1 + 512);
    bn_finalize<<<1, 256, 0, stream>>>(fs1, fs1 + 512, g2, b2, scale, shift, 128, 1, 1.f/65536.f);
    bn_act16<<<4096, 256, 0, stream>>>(slotA, scale, shift, 127, 0.2f);

    // ---- conv3 (SPT=128): slotA(lo) -> A_hi, 512 blocks ----
    mfma_conv<128,16,16,8,8,256, 64,128,1,1,false><<<dim3(128,4,1), 256, 0, stream>>>(
        slotA, wprep + 131072, A_hi, nullptr, 0, fs2, fs2 + 512);
    bn_finalize<<<1, 256, 0, stream>>>(fs2, fs2 + 512, g3, b3, scale, shift, 256, 1, 1.f/16384.f);
    bn_act16<<<2048, 256, 0, stream>>>(A_hi, scale, shift, 255, 0.2f);

    // ---- conv4 (SPT=128, KS=1 now!): A_hi -> slotA(lo), 256 blocks ----
    mfma_conv<256,8,8,4,4,512, 64,128,1,1,false><<<dim3(32,8,1), 256, 0, stream>>>(
        A_hi, wprep + 655360, slotA, nullptr, 0, fs3, fs3 + 512);
    bn_finalize<<<2, 256, 0, stream>>>(fs3, fs3 + 512, g4, b4, scale, shift, 512, 1, 1.f/4096.f);
    bn_act16<<<1024, 256, 0, stream>>>(slotA, scale, shift, 511, 0.2f);

    // ---- channel-wise linear: slotA(lo) -> slotB(lo) ----
    chanlin16<<<8192, 256, 0, stream>>>(slotA, cww, cwb, slotB);

    // ---- deconv1 (SPT=128): slotB(lo) -> A_hi, 512 blocks ----
    mfma_conv<512,4,4,8,8,256, 64,128,1,1,true><<<dim3(32,4,4), 256, 0, stream>>>(
        slotB, wprep + 2752512, A_hi, nullptr, 0, fs4, fs4 + 512);
    bn_finalize<<<1, 256, 0, stream>>>(fs4, fs4 + 512, dg1, db1, scale, shift, 256, 1, 1.f/16384.f);
    bn_act16<<<2048, 256, 0, stream>>>(A_hi, scale, shift, 255, 0.f);

    // ---- deconv2 (SPT=128): A_hi -> slotB(lo), 1024 blocks ----
    mfma_conv<256,8,8,16,16,128, 64,128,1,1,true><<<dim3(128,2,4), 256, 0, stream>>>(
        A_hi, wprep + 4849664, slotB, nullptr, 0, fs5, fs5 + 512);
    bn_finalize<<<1, 256, 0, stream>>>(fs5, fs5 + 512, dg2, db2, scale, shift, 128, 1, 1.f/65536.f);
    bn_act16<<<4096, 256, 0, stream>>>(slotB, scale, shift, 127, 0.f);

    // ---- deconv3 (SPT=128): slotB(lo) -> slotA full, 2048 blocks ----
    mfma_conv<128,16,16,32,32,64, 64,128,1,1,true><<<dim3(512,1,4), 256, 0, stream>>>(
        slotB, wprep + 5373952, slotA, nullptr, 0, fs6, fs6 + 512);
    bn_finalize<<<1, 256, 0, stream>>>(fs6, fs6 + 512, dg3, db3, scale, shift, 64, 1, 1.f/262144.f);
    bn_act16<<<8192, 256, 0, stream>>>(slotA, scale, shift, 63, 0.f);

    // ---- deconv4 (MFMA) + tanh: slotA -> d_out ----
    deconv4_mfma<<<dim3(1024,4), 256, 0, stream>>>(slotA, wprep4, (float*)d_out);
}

// Round 12
// 718.551 us; speedup vs baseline: 1.0339x; 1.0339x over previous
//
#include <hip/hip_runtime.h>
#include <math.h>

typedef _Float16 f16;
typedef __attribute__((ext_vector_type(8))) _Float16 f16x8;
typedef __attribute__((ext_vector_type(16))) float f32x16;

union U64x2 { unsigned long long u[2]; f16x8 v; };
union Q16   { uint4 q; unsigned long long u[2]; };

constexpr int ilog2c(int x) { return x <= 1 ? 0 : 1 + ilog2c(x >> 1); }

__device__ __forceinline__ float fast_tanh(float x) {
    float e = __expf(2.f * x);
    return (e - 1.f) / (e + 1.f);
}

// ===========================================================================
// fp16 MFMA implicit-GEMM conv/deconv (k4 s2 p1), NHWC activations.
// SPT=256 (round-10 verified geometry; SPT=128 regressed — per-chunk
// W-staging/barrier overhead doubles with block count). A=X, B=W =>
// D: row=sp, col=co. KS>1: disjoint f32 partials. KS==1: fused BN stats.
// ===========================================================================
template<int CIN,int IH,int IW,int OH,int OW,int COUT,int COB,int SPT,int KS,
         int CO_FR,bool DEC>
__global__ __launch_bounds__(256,2) void mfma_conv(
    const f16* __restrict__ xin, const f16* __restrict__ wp,
    f16* __restrict__ out16, float* __restrict__ out32, size_t ps,
    float* __restrict__ psumF, float* __restrict__ psqF)
{
    constexpr int OHo  = DEC ? OH/2 : OH;
    constexpr int OWo  = DEC ? OW/2 : OW;
    constexpr int KTOT = CIN * (DEC ? 4 : 16);
    constexpr int CH   = (KTOT/64) / KS;
    constexpr int RPT  = CIN / 64;
    constexpr int RSH  = (RPT==1?0:RPT==2?1:RPT==4?2:3);
    constexpr int WSTR = CIN * 16;
    constexpr int TPR  = 256 / COB;
    constexpr int NU4  = 8 / TPR;
    constexpr int SPB  = OHo * OWo;
    constexpr int LSPB = ilog2c(SPB);
    constexpr int LOWo = ilog2c(OWo);

    __shared__ unsigned long long Xs[SPT*17];
    __shared__ unsigned long long Wls[COB*17];

    const int t   = threadIdx.x;
    const int bx  = blockIdx.x;
    const int cob = blockIdx.y;
    const int bz  = blockIdx.z;
    const int par = DEC ? (bz & 3) : 0;
    const int ks  = DEC ? (bz >> 2) : bz;
    const int poh = par >> 1, pw = par & 1;

    const int gsp_s = bx*SPT + t;
    const int img_s = gsp_s >> LSPB;
    const int r_s   = gsp_s & (SPB-1);
    const int oy_s  = r_s >> LOWo;
    const int ox_s  = r_s & (OWo-1);

    const int wco   = t / TPR;
    const int wpart = t % TPR;
    const f16* wbase = wp + (size_t)(cob*COB + wco)*WSTR + wpart*(64/TPR);

    const int wave = t >> 6, lane = t & 63, half = lane >> 5, l31 = lane & 31;
    const int co_w = (wave >> 1) * (CO_FR*32);
    const int sp_w = (wave & 1) * 128;

    f32x16 acc[CO_FR][4];
    #pragma unroll
    for (int i = 0; i < CO_FR; ++i)
        #pragma unroll
        for (int b = 0; b < 4; ++b)
            #pragma unroll
            for (int r = 0; r < 16; ++r) acc[i][b][r] = 0.f;

    for (int cc = 0; cc < CH; ++cc) {
        const int gc  = ks*CH + cc;
        const int tap = gc >> RSH;
        const int ci0 = (gc & (RPT-1)) << 6;
        int kh, kw, ih, iw;
        if (DEC) {
            const int t2h = tap >> 1, t2w = tap & 1;
            kh = (1-poh) + 2*t2h; kw = (1-pw) + 2*t2w;
            ih = oy_s + poh - t2h; iw = ox_s + pw - t2w;
        } else {
            kh = tap >> 2; kw = tap & 3;
            ih = 2*oy_s - 1 + kh; iw = 2*ox_s - 1 + kw;
        }
        const int woff = (kh*4 + kw)*CIN + ci0;

        if (cc) __syncthreads();
        {
            const uint4* src = (const uint4*)(wbase + woff);
            #pragma unroll
            for (int j = 0; j < NU4; ++j) {
                Q16 v; v.q = src[j];
                const int u0 = wco*17 + wpart*(NU4*2) + j*2;
                Wls[u0]   = v.u[0];
                Wls[u0+1] = v.u[1];
            }
        }
        {
            const bool ok = (unsigned)ih < (unsigned)IH && (unsigned)iw < (unsigned)IW;
            const int u0 = t*17;
            if (ok) {
                const uint4* src = (const uint4*)
                    (xin + ((size_t)(img_s*IH + ih)*IW + iw)*CIN + ci0);
                #pragma unroll
                for (int j = 0; j < 8; ++j) {
                    Q16 v; v.q = src[j];
                    Xs[u0 + j*2]   = v.u[0];
                    Xs[u0 + j*2+1] = v.u[1];
                }
            } else {
                #pragma unroll
                for (int j = 0; j < 16; ++j) Xs[u0 + j] = 0ull;
            }
        }
        __syncthreads();

        #pragma unroll
        for (int kk = 0; kk < 4; ++kk) {
            const int uo = kk*4 + 2*half;
            f16x8 wf[CO_FR], xf[4];
            #pragma unroll
            for (int i = 0; i < CO_FR; ++i) {
                U64x2 u; const int rw = (co_w + i*32 + l31)*17 + uo;
                u.u[0] = Wls[rw]; u.u[1] = Wls[rw+1]; wf[i] = u.v;
            }
            #pragma unroll
            for (int b = 0; b < 4; ++b) {
                U64x2 u; const int rx = (sp_w + b*32 + l31)*17 + uo;
                u.u[0] = Xs[rx]; u.u[1] = Xs[rx+1]; xf[b] = u.v;
            }
            #pragma unroll
            for (int i = 0; i < CO_FR; ++i)
                #pragma unroll
                for (int b = 0; b < 4; ++b)
                    acc[i][b] = __builtin_amdgcn_mfma_f32_32x32x16_f16(
                        xf[b], wf[i], acc[i][b], 0, 0, 0);
        }
    }

    #pragma unroll
    for (int b = 0; b < 4; ++b) {
        #pragma unroll
        for (int q = 0; q < 4; ++q) {
            #pragma unroll
            for (int r2 = 0; r2 < 4; ++r2) {
                const int sp_loc = sp_w + b*32 + q*8 + 4*half + r2;
                const int gsp    = bx*SPT + sp_loc;
                size_t base;
                if (DEC) {
                    const int img = gsp >> LSPB;
                    const int r   = gsp & (SPB-1);
                    const int oh  = 2*(r >> LOWo) + poh;
                    const int ow  = 2*(r & (OWo-1)) + pw;
                    base = ((size_t)(img*OH + oh)*OW + ow)*COUT + cob*COB;
                } else {
                    base = (size_t)gsp*COUT + cob*COB;
                }
                #pragma unroll
                for (int i = 0; i < CO_FR; ++i) {
                    const int co_l = co_w + i*32 + l31;
                    const float v  = acc[i][b][q*4 + r2];
                    if (KS == 1) out16[base + co_l] = (_Float16)v;
                    else         out32[(size_t)ks*ps + base + co_l] = v;
                }
            }
        }
    }

    if (KS == 1 && psumF != nullptr) {
        #pragma unroll
        for (int i = 0; i < CO_FR; ++i) {
            float s = 0.f, q = 0.f;
            #pragma unroll
            for (int b = 0; b < 4; ++b)
                #pragma unroll
                for (int r = 0; r < 16; ++r) {
                    const float v = acc[i][b][r];
                    s += v; q += v * v;
                }
            s += __shfl_down(s, 32);
            q += __shfl_down(q, 32);
            if (half == 0) {
                const int co = cob*COB + co_w + i*32 + l31;
                atomicAdd(psumF + co, s);
                atomicAdd(psqF + co, q);
            }
        }
    }
}

// ---------------------------------------------------------------------------
// conv1 via MFMA + fused BN stats (verified rounds 8-10)
// ---------------------------------------------------------------------------
__global__ __launch_bounds__(256,2) void conv1_mfma(
    const f16* __restrict__ xp, const f16* __restrict__ wp,
    f16* __restrict__ out, float* __restrict__ psumF, float* __restrict__ psqF)
{
    __shared__ unsigned long long Xs[256*17];
    __shared__ unsigned long long Wls[64*17];
    const int t = threadIdx.x, bx = blockIdx.x;

    {
        const int r = t >> 2, part = t & 3;
        const uint4* src = (const uint4*)(wp + r*64 + part*16);
        Q16 v0; v0.q = src[0];
        Q16 v1; v1.q = src[1];
        const int u0 = r*17 + part*4;
        Wls[u0]   = v0.u[0]; Wls[u0+1] = v0.u[1];
        Wls[u0+2] = v1.u[0]; Wls[u0+3] = v1.u[1];
    }
    {
        const int gsp = bx*256 + t;
        const int n = gsp >> 10, r = gsp & 1023;
        const int oy = r >> 5, ox = r & 31;
        const int ih0 = 2*oy - 1, iw0 = 2*ox - 1;
        const int u0 = t*17;
        #pragma unroll
        for (int tap = 0; tap < 16; ++tap) {
            const int ih = ih0 + (tap >> 2), iw = iw0 + (tap & 3);
            unsigned long long v = 0ull;
            if ((unsigned)ih < 64u && (unsigned)iw < 64u)
                v = *(const unsigned long long*)(xp + (((size_t)n*64 + ih)*64 + iw)*4);
            Xs[u0 + tap] = v;
        }
    }
    __syncthreads();

    const int wave = t >> 6, lane = t & 63, half = lane >> 5, l31 = lane & 31;
    const int co_w = (wave >> 1) * 32;
    const int sp_w = (wave & 1) * 128;

    f32x16 acc[4];
    #pragma unroll
    for (int b = 0; b < 4; ++b)
        #pragma unroll
        for (int r = 0; r < 16; ++r) acc[b][r] = 0.f;

    #pragma unroll
    for (int kk = 0; kk < 4; ++kk) {
        const int uo = kk*4 + 2*half;
        U64x2 uw; const int rw = (co_w + l31)*17 + uo;
        uw.u[0] = Wls[rw]; uw.u[1] = Wls[rw+1];
        #pragma unroll
        for (int b = 0; b < 4; ++b) {
            U64x2 ux; const int rx = (sp_w + b*32 + l31)*17 + uo;
            ux.u[0] = Xs[rx]; ux.u[1] = Xs[rx+1];
            acc[b] = __builtin_amdgcn_mfma_f32_32x32x16_f16(
                ux.v, uw.v, acc[b], 0, 0, 0);
        }
    }
    #pragma unroll
    for (int b = 0; b < 4; ++b)
        #pragma unroll
        for (int q = 0; q < 4; ++q)
            #pragma unroll
            for (int r2 = 0; r2 < 4; ++r2) {
                const int sp_loc = sp_w + b*32 + q*8 + 4*half + r2;
                out[(size_t)(bx*256 + sp_loc)*64 + co_w + l31] =
                    (_Float16)acc[b][q*4 + r2];
            }

    float s = 0.f, q = 0.f;
    #pragma unroll
    for (int b = 0; b < 4; ++b)
        #pragma unroll
        for (int r = 0; r < 16; ++r) {
            const float v = acc[b][r];
            s += v; q += v * v;
        }
    s += __shfl_down(s, 32);
    q += __shfl_down(q, 32);
    if (half == 0) {
        const int co = co_w + l31;
        atomicAdd(psumF + co, s);
        atomicAdd(psqF + co, q);
    }
}

// ---------------------------------------------------------------------------
// deconv4 (64->3) via MFMA, COUT padded to 32 (verified round 9)
// ---------------------------------------------------------------------------
__global__ __launch_bounds__(256,2) void deconv4_mfma(
    const f16* __restrict__ xin, const f16* __restrict__ wp,
    float* __restrict__ out)
{
    __shared__ unsigned long long Xs[256*17];
    __shared__ unsigned long long Wls[32*17];

    const int t   = threadIdx.x;
    const int bx  = blockIdx.x;
    const int par = blockIdx.y;
    const int poh = par >> 1, pw = par & 1;

    const int gsp_s = bx*256 + t;
    const int img_s = gsp_s >> 10;
    const int r_s   = gsp_s & 1023;
    const int oy_s  = r_s >> 5;
    const int ox_s  = r_s & 31;

    const int wco   = t >> 3;
    const int wpart = t & 7;

    const int wave = t >> 6, lane = t & 63, half = lane >> 5, l31 = lane & 31;
    const int sp_w = wave * 64;

    f32x16 acc[2];
    #pragma unroll
    for (int b = 0; b < 2; ++b)
        #pragma unroll
        for (int r = 0; r < 16; ++r) acc[b][r] = 0.f;

    for (int cc = 0; cc < 4; ++cc) {
        const int t2h = cc >> 1, t2w = cc & 1;
        const int kh = (1-poh) + 2*t2h, kw = (1-pw) + 2*t2w;
        const int ih = oy_s + poh - t2h, iw = ox_s + pw - t2w;

        if (cc) __syncthreads();
        {
            Q16 v; v.q = *(const uint4*)(wp + wco*1024 + (kh*4 + kw)*64 + wpart*8);
            const int u0 = wco*17 + wpart*2;
            Wls[u0] = v.u[0]; Wls[u0+1] = v.u[1];
        }
        {
            const bool ok = (unsigned)ih < 32u && (unsigned)iw < 32u;
            const int u0 = t*17;
            if (ok) {
                const uint4* src = (const uint4*)
                    (xin + ((size_t)(img_s*32 + ih)*32 + iw)*64);
                #pragma unroll
                for (int j = 0; j < 8; ++j) {
                    Q16 v; v.q = src[j];
                    Xs[u0 + j*2]   = v.u[0];
                    Xs[u0 + j*2+1] = v.u[1];
                }
            } else {
                #pragma unroll
                for (int j = 0; j < 16; ++j) Xs[u0 + j] = 0ull;
            }
        }
        __syncthreads();

        #pragma unroll
        for (int kk = 0; kk < 4; ++kk) {
            const int uo = kk*4 + 2*half;
            U64x2 uw; const int rw = l31*17 + uo;
            uw.u[0] = Wls[rw]; uw.u[1] = Wls[rw+1];
            #pragma unroll
            for (int b = 0; b < 2; ++b) {
                U64x2 ux; const int rx = (sp_w + b*32 + l31)*17 + uo;
                ux.u[0] = Xs[rx]; ux.u[1] = Xs[rx+1];
                acc[b] = __builtin_amdgcn_mfma_f32_32x32x16_f16(
                    uw.v, ux.v, acc[b], 0, 0, 0);
            }
        }
    }

    if (half == 0) {
        #pragma unroll
        for (int b = 0; b < 2; ++b) {
            const int gsp = bx*256 + sp_w + b*32 + l31;
            const int img = gsp >> 10;
            const int r   = gsp & 1023;
            const int oh  = 2*(r >> 5) + poh;
            const int ow  = 2*(r & 31) + pw;
            #pragma unroll
            for (int co = 0; co < 3; ++co)
                out[(((size_t)img*3 + co)*64 + oh)*64 + ow] =
                    fast_tanh(acc[b][co]);
        }
    }
}

// ---------------------------------------------------------------------------
// prep kernels (verified)
// ---------------------------------------------------------------------------
__global__ __launch_bounds__(256) void prep_x(
    const float* __restrict__ x, f16* __restrict__ xp)
{
    const int i = blockIdx.x*256 + threadIdx.x;
    const int n = i >> 12, p = i & 4095;
    const float* b = x + (size_t)n*12288 + p;
    union { _Float16 h[4]; unsigned long long u; } o;
    o.h[0] = (_Float16)b[0];
    o.h[1] = (_Float16)b[4096];
    o.h[2] = (_Float16)b[8192];
    o.h[3] = (_Float16)0.f;
    *(unsigned long long*)(xp + (size_t)i*4) = o.u;
}

__global__ __launch_bounds__(256) void prep_w1(
    const float* __restrict__ w1, f16* __restrict__ wp)
{
    const int e = blockIdx.x*256 + threadIdx.x;
    const int co = e >> 6, k = e & 63, tap = k >> 2, ci = k & 3;
    const float v = (ci < 3) ? w1[(co*3 + ci)*16 + tap] : 0.f;
    wp[e] = (_Float16)v;
}

__global__ __launch_bounds__(256) void prep_w4(
    const float* __restrict__ dw4, f16* __restrict__ wp)
{
    const int e = blockIdx.x*256 + threadIdx.x;
    const int co = e >> 10, r = e & 1023, khw = r >> 6, ci = r & 63;
    const float v = (co < 3) ? dw4[(ci*3 + co)*16 + khw] : 0.f;
    wp[e] = (_Float16)v;
}

__global__ __launch_bounds__(256) void prep_w(
    const float* __restrict__ w2, const float* __restrict__ w3,
    const float* __restrict__ w4, const float* __restrict__ dw1,
    const float* __restrict__ dw2, const float* __restrict__ dw3,
    f16* __restrict__ dst)
{
    const int e = blockIdx.x*256 + threadIdx.x;
    float v;
    if (e < 131072) {
        int co = e >> 10, r = e & 1023, khw = r >> 6, ci = r & 63;
        v = w2[(co*64 + ci)*16 + khw];
    } else if (e < 655360) {
        int l = e - 131072;
        int co = l >> 11, r = l & 2047, khw = r >> 7, ci = r & 127;
        v = w3[(co*128 + ci)*16 + khw];
    } else if (e < 2752512) {
        int l = e - 655360;
        int co = l >> 12, r = l & 4095, khw = r >> 8, ci = r & 255;
        v = w4[(co*256 + ci)*16 + khw];
    } else if (e < 4849664) {
        int l = e - 2752512;
        int co = l >> 13, r = l & 8191, khw = r >> 9, ci = r & 511;
        v = dw1[(ci*256 + co)*16 + khw];
    } else if (e < 5373952) {
        int l = e - 4849664;
        int co = l >> 12, r = l & 4095, khw = r >> 8, ci = r & 255;
        v = dw2[(ci*128 + co)*16 + khw];
    } else {
        int l = e - 5373952;
        int co = l >> 11, r = l & 2047, khw = r >> 7, ci = r & 127;
        v = dw3[(ci*64 + co)*16 + khw];
    }
    dst[e] = (_Float16)v;
}

// ---------------------------------------------------------------------------
// BN: conv4 chain keeps partial+finalize; all other layers use bn_act16f
// (finalize merged: per-thread scale/shift from psum/psq, tiny cached reads).
// ---------------------------------------------------------------------------
template<typename T, int P>
__global__ __launch_bounds__(256) void bn_partial(
    const T* __restrict__ x, size_t ps, float* __restrict__ psum,
    float* __restrict__ psq, int C, int rowsPerS, int S)
{
    const int s = blockIdx.x;
    const int c = (blockIdx.y << 6) + (threadIdx.x & 63);
    float a = 0.f, q = 0.f;
    const int rEnd = (s + 1) * rowsPerS;
    for (int r = s*rowsPerS + (threadIdx.x >> 6); r < rEnd; r += 4) {
        float v = 0.f;
        #pragma unroll
        for (int p = 0; p < P; ++p)
            v += (float)x[p*ps + (size_t)r * C + c];
        a += v; q += v * v;
    }
    __shared__ float ls[256], lq[256];
    ls[threadIdx.x] = a; lq[threadIdx.x] = q;
    __syncthreads();
    if (threadIdx.x < 64) {
        a = ls[threadIdx.x] + ls[threadIdx.x+64] + ls[threadIdx.x+128] + ls[threadIdx.x+192];
        q = lq[threadIdx.x] + lq[threadIdx.x+64] + lq[threadIdx.x+128] + lq[threadIdx.x+192];
        psum[c * S + s] = a; psq[c * S + s] = q;
    }
}

__global__ __launch_bounds__(256) void bn_finalize(
    const float* __restrict__ psum, const float* __restrict__ psq,
    const float* __restrict__ gamma, const float* __restrict__ beta,
    float* __restrict__ scale, float* __restrict__ shift,
    int C, int S, float inv_count)
{
    int c = blockIdx.x * 256 + threadIdx.x;
    if (c >= C) return;
    float s = 0.f, q = 0.f;
    for (int i = 0; i < S; ++i) { s += psum[c*S + i]; q += psq[c*S + i]; }
    float m   = s * inv_count;
    float var = q * inv_count - m * m;
    var = var < 0.f ? 0.f : var;
    float sc = gamma[c] * rsqrtf(var + 1e-5f);
    scale[c] = sc;
    shift[c] = beta[c] - m * sc;
}

// affine+act with finalize fused (S=1 fused-stat layers)
__global__ __launch_bounds__(256) void bn_act16f(
    f16* __restrict__ x, const float* __restrict__ psum, const float* __restrict__ psq,
    const float* __restrict__ gamma, const float* __restrict__ beta,
    int Cmask, float inv_count, float slope)
{
    const size_t i8 = ((size_t)blockIdx.x*256 + threadIdx.x) * 8;
    union { uint4 u; _Float16 h[8]; } a;
    a.u = *(const uint4*)(x + i8);
    const int c0 = (int)(i8 & (size_t)Cmask);
    #pragma unroll
    for (int j = 0; j < 8; ++j) {
        const int c = c0 + j;
        float m   = psum[c] * inv_count;
        float var = psq[c] * inv_count - m * m;
        var = var < 0.f ? 0.f : var;
        float sc = gamma[c] * rsqrtf(var + 1e-5f);
        float sh = beta[c] - m * sc;
        float v = (float)a.h[j] * sc + sh;
        a.h[j] = (_Float16)(v >= 0.f ? v : slope * v);
    }
    *(uint4*)(x + i8) = a.u;
}

template<int P>
__global__ __launch_bounds__(256) void bn_act32(
    const float* __restrict__ x, size_t ps, f16* __restrict__ y,
    const float* __restrict__ sc, const float* __restrict__ sh,
    int Cmask, float slope)
{
    const size_t i8 = ((size_t)blockIdx.x*256 + threadIdx.x) * 8;
    float xv[8] = {0,0,0,0,0,0,0,0};
    #pragma unroll
    for (int p = 0; p < P; ++p) {
        float4 v0 = *(const float4*)(x + p*ps + i8);
        float4 v1 = *(const float4*)(x + p*ps + i8 + 4);
        xv[0]+=v0.x; xv[1]+=v0.y; xv[2]+=v0.z; xv[3]+=v0.w;
        xv[4]+=v1.x; xv[5]+=v1.y; xv[6]+=v1.z; xv[7]+=v1.w;
    }
    union { uint4 u; _Float16 h[8]; } a;
    const int c0 = (int)(i8 & (size_t)Cmask);
    #pragma unroll
    for (int j = 0; j < 8; ++j) {
        float v = xv[j] * sc[c0+j] + sh[c0+j];
        a.h[j] = (_Float16)(v >= 0.f ? v : slope * v);
    }
    *(uint4*)(y + i8) = a.u;
}

__global__ __launch_bounds__(256) void chanlin16(
    const f16* __restrict__ in, const float* __restrict__ w,
    const float* __restrict__ bias, f16* __restrict__ out)
{
    const int i = blockIdx.x*256 + threadIdx.x;
    const int c  = i & 511;
    const int bt = i >> 9;
    const int b  = bt >> 4, tt = bt & 15;
    const f16* src = in + ((size_t)b*16)*512 + c;
    const float* wr = w + ((size_t)c*16 + tt)*16;
    float acc = bias[c*16 + tt];
    #pragma unroll
    for (int s = 0; s < 16; ++s)
        acc = fmaf((float)src[s*512], wr[s], acc);
    out[i] = (_Float16)acc;
}

extern "C" void kernel_launch(void* const* d_in, const int* in_sizes, int n_in,
                              void* d_out, int out_size, void* d_ws, size_t ws_size,
                              hipStream_t stream)
{
    const float* x   = (const float*)d_in[0];
    const float* w1  = (const float*)d_in[1];
    const float* w2  = (const float*)d_in[2];
    const float* w3  = (const float*)d_in[3];
    const float* w4  = (const float*)d_in[4];
    const float* g1  = (const float*)d_in[5];
    const float* b1  = (const float*)d_in[6];
    const float* g2  = (const float*)d_in[7];
    const float* b2  = (const float*)d_in[8];
    const float* g3  = (const float*)d_in[9];
    const float* b3  = (const float*)d_in[10];
    const float* g4  = (const float*)d_in[11];
    const float* b4  = (const float*)d_in[12];
    const float* cww = (const float*)d_in[13];
    const float* cwb = (const float*)d_in[14];
    const float* dw1 = (const float*)d_in[15];
    const float* dw2 = (const float*)d_in[16];
    const float* dw3 = (const float*)d_in[17];
    const float* dw4 = (const float*)d_in[18];
    const float* dg1 = (const float*)d_in[19];
    const float* db1 = (const float*)d_in[20];
    const float* dg2 = (const float*)d_in[21];
    const float* db2 = (const float*)d_in[22];
    const float* dg3 = (const float*)d_in[23];
    const float* db3 = (const float*)d_in[24];

    char* WS = (char*)d_ws;
    float* psum  = (float*)WS;
    float* psq   = (float*)(WS + 65536);
    float* scale = (float*)(WS + 131072);
    float* shift = (float*)(WS + 133120);
    float* fst   = (float*)(WS + 196608);
    f16* slotA   = (f16*)(WS + 262144);
    f16* slotB   = (f16*)(WS + 262144 + 33554432);
    f16* wprep   = (f16*)(WS + 84148224);
    f16* wprep1  = wprep + 5505024;
    f16* wprep4  = wprep1 + 4096;

    f16*   A_hi  = slotA + 8388608;
    float* pB    = (float*)slotB;
    f16*   xpack = slotA;

    float* fs0 = fst;          float* fs1 = fst + 1024;
    float* fs2 = fst + 2048;   float* fs4 = fst + 4096;
    float* fs5 = fst + 5120;   float* fs6 = fst + 6144;

    hipMemsetAsync(fst, 0, 28672, stream);
    prep_w<<<21504, 256, 0, stream>>>(w2, w3, w4, dw1, dw2, dw3, wprep);
    prep_w1<<<16, 256, 0, stream>>>(w1, wprep1);
    prep_w4<<<128, 256, 0, stream>>>(dw4, wprep4);
    prep_x<<<4096, 256, 0, stream>>>(x, xpack);

    // ---- conv1 (MFMA + fused stats): xpack(slotA) -> slotB ----
    conv1_mfma<<<1024, 256, 0, stream>>>(xpack, wprep1, slotB, fs0, fs0 + 512);
    bn_act16f<<<8192, 256, 0, stream>>>(slotB, fs0, fs0 + 512, g1, b1, 63, 1.f/262144.f, 0.2f);

    // ---- conv2 (fused stats): slotB -> slotA ----
    mfma_conv<64,32,32,16,16,128, 128,256,1,2,false><<<dim3(256,1,1), 256, 0, stream>>>(
        slotB, wprep, slotA, nullptr, 0, fs1, fs1 + 512);
    bn_act16f<<<4096, 256, 0, stream>>>(slotA, fs1, fs1 + 512, g2, b2, 127, 1.f/65536.f, 0.2f);

    // ---- conv3 (KS=1, COB=64, fused stats): slotA -> A_hi f16 ----
    mfma_conv<128,16,16,8,8,256, 64,256,1,1,false><<<dim3(64,4,1), 256, 0, stream>>>(
        slotA, wprep + 131072, A_hi, nullptr, 0, fs2, fs2 + 512);
    bn_act16f<<<2048, 256, 0, stream>>>(A_hi, fs2, fs2 + 512, g3, b3, 255, 1.f/16384.f, 0.2f);

    // ---- conv4 (KS=4, partials in slotB): A_hi -> pB ----
    mfma_conv<256,8,8,4,4,512, 128,256,4,2,false><<<dim3(16,4,4), 256, 0, stream>>>(
        A_hi, wprep + 655360, nullptr, pB, (size_t)2097152, nullptr, nullptr);
    bn_partial<float,4><<<dim3(32,8), 256, 0, stream>>>(pB, (size_t)2097152, psum, psq, 512, 128, 32);
    bn_finalize<<<2, 256, 0, stream>>>(psum, psq, g4, b4, scale, shift, 512, 32, 1.f/4096.f);
    bn_act32<4><<<1024, 256, 0, stream>>>(pB, (size_t)2097152, slotA, scale, shift, 511, 0.2f);

    // ---- channel-wise linear: slotA(lo) -> slotB(lo) ----
    chanlin16<<<8192, 256, 0, stream>>>(slotA, cww, cwb, slotB);

    // ---- deconv1 (KS=1, COB=64, fused stats): slotB(lo) -> A_hi ----
    mfma_conv<512,4,4,8,8,256, 64,256,1,1,true><<<dim3(16,4,4), 256, 0, stream>>>(
        slotB, wprep + 2752512, A_hi, nullptr, 0, fs4, fs4 + 512);
    bn_act16f<<<2048, 256, 0, stream>>>(A_hi, fs4, fs4 + 512, dg1, db1, 255, 1.f/16384.f, 0.f);

    // ---- deconv2 (fused stats): A_hi -> slotB(lo) ----
    mfma_conv<256,8,8,16,16,128, 128,256,1,2,true><<<dim3(64,1,4), 256, 0, stream>>>(
        A_hi, wprep + 4849664, slotB, nullptr, 0, fs5, fs5 + 512);
    bn_act16f<<<4096, 256, 0, stream>>>(slotB, fs5, fs5 + 512, dg2, db2, 127, 1.f/65536.f, 0.f);

    // ---- deconv3 (COB=64, fused stats): slotB(lo) -> slotA full ----
    mfma_conv<128,16,16,32,32,64, 64,256,1,1,true><<<dim3(256,1,4), 256, 0, stream>>>(
        slotB, wprep + 5373952, slotA, nullptr, 0, fs6, fs6 + 512);
    bn_act16f<<<8192, 256, 0, stream>>>(slotA, fs6, fs6 + 512, dg3, db3, 63, 1.f/262144.f, 0.f);

    // ---- deconv4 (MFMA) + tanh: slotA -> d_out ----
    deconv4_mfma<<<dim3(1024,4), 256, 0, stream>>>(slotA, wprep4, (float*)d_out);
}